// Round 1
// baseline (9128.057 us; speedup 1.0000x reference)
//
#include <hip/hip_runtime.h>
#include <stdint.h>

#define B_    32
#define T_    512
#define H_    1024
#define H3_   3072
#define EMB_  512

typedef __bf16   bf16x8 __attribute__((ext_vector_type(8)));
typedef float    f32x4  __attribute__((ext_vector_type(4)));
typedef uint32_t u32x4  __attribute__((ext_vector_type(4)));

__device__ __forceinline__ uint32_t f2bf_rne_u(float x){
  union { float f; uint32_t u; } v; v.f = x;
  uint32_t u = v.u;
  return (u + 0x7FFFu + ((u >> 16) & 1u)) >> 16;
}
__device__ __forceinline__ float bf2f(uint32_t h16){
  union { uint32_t u; float f; } v; v.u = h16 << 16; return v.f;
}
__device__ __forceinline__ float sigm(float x){ return 1.f / (1.f + __expf(-x)); }
__device__ __forceinline__ float tanh_f(float x){ float e = __expf(2.f * x); return 1.f - 2.f / (e + 1.f); }

__device__ __forceinline__ f32x4 mfma16(bf16x8 a, bf16x8 b, f32x4 c){
  return __builtin_amdgcn_mfma_f32_16x16x32_bf16(a, b, c, 0, 0, 0);
}
// 8 packed u32 (hi16|lo16 per element) -> hi-halves / lo-halves as bf16x8
__device__ __forceinline__ bf16x8 upk_hi(u32x4 a, u32x4 b){
  u32x4 r;
  r.x = (a.x >> 16) | (a.y & 0xFFFF0000u);
  r.y = (a.z >> 16) | (a.w & 0xFFFF0000u);
  r.z = (b.x >> 16) | (b.y & 0xFFFF0000u);
  r.w = (b.z >> 16) | (b.w & 0xFFFF0000u);
  return __builtin_bit_cast(bf16x8, r);
}
__device__ __forceinline__ bf16x8 upk_lo(u32x4 a, u32x4 b){
  u32x4 r;
  r.x = (a.x & 0xFFFFu) | (a.y << 16);
  r.y = (a.z & 0xFFFFu) | (a.w << 16);
  r.z = (b.x & 0xFFFFu) | (b.y << 16);
  r.w = (b.z & 0xFFFFu) | (b.w << 16);
  return __builtin_bit_cast(bf16x8, r);
}

// ---------------- prep kernels ----------------

__global__ void k_emb2bf(const float* __restrict__ src, unsigned short* __restrict__ dst, int n8){
  int i = blockIdx.x * blockDim.x + threadIdx.x;
  if (i >= n8) return;
  const float4* s = (const float4*)src + (size_t)i * 2;
  float4 x = s[0], y = s[1];
  u32x4 o;
  o.x = f2bf_rne_u(x.x) | (f2bf_rne_u(x.y) << 16);
  o.y = f2bf_rne_u(x.z) | (f2bf_rne_u(x.w) << 16);
  o.z = f2bf_rne_u(y.x) | (f2bf_rne_u(y.y) << 16);
  o.w = f2bf_rne_u(y.z) | (f2bf_rne_u(y.w) << 16);
  ((u32x4*)dst)[i] = o;
}

// W (EMB x 3H) -> MFMA B-fragment layout [d][ct(64)][p(3)][ks(16)][lane(64)][8], bf16
__global__ void k_packW(const float* __restrict__ Wf, const float* __restrict__ Wb,
                        unsigned short* __restrict__ out){
  int idx = blockIdx.x * 256 + threadIdx.x;            // 2*64*3*16*64 = 393216
  int lane = idx & 63;
  int ks   = (idx >> 6) & 15;
  int rest = idx >> 10;                                 // d*192 + ct*3 + p
  int p  = rest % 3;
  int ct = (rest / 3) & 63;
  int d  = rest / 192;
  const float* W = d ? Wb : Wf;
  int colg = p * 1024 + ct * 16 + (lane & 15);
  int k0   = ks * 32 + ((lane >> 4) << 3);
  unsigned short* o = out + (size_t)idx * 8;
  #pragma unroll
  for (int b = 0; b < 8; ++b)
    o[b] = (unsigned short)f2bf_rne_u(W[(size_t)(k0 + b) * H3_ + colg]);
}

// U (H x 3H) -> hi/lo split fragment layout [d][ct][p][ks(32)][lane][8]
__global__ void k_packU(const float* __restrict__ Uf, const float* __restrict__ Ub,
                        unsigned short* __restrict__ ohi, unsigned short* __restrict__ olo){
  int idx = blockIdx.x * 256 + threadIdx.x;            // 2*64*3*32*64 = 786432
  int lane = idx & 63;
  int ks   = (idx >> 6) & 31;
  int rest = idx >> 11;                                 // d*192 + ct*3 + p
  int p  = rest % 3;
  int ct = (rest / 3) & 63;
  int d  = rest / 192;
  const float* U = d ? Ub : Uf;
  int colg = p * 1024 + ct * 16 + (lane & 15);
  int k0   = ks * 32 + ((lane >> 4) << 3);
  size_t o = (size_t)idx * 8;
  #pragma unroll
  for (int b = 0; b < 8; ++b){
    float u = U[(size_t)(k0 + b) * H3_ + colg];
    uint32_t hi = f2bf_rne_u(u);
    float lo = u - bf2f(hi);
    ohi[o + b] = (unsigned short)hi;
    olo[o + b] = (unsigned short)f2bf_rne_u(lo);
  }
}

__global__ void k_add(float* __restrict__ out, const float* __restrict__ add, int n4){
  int i = blockIdx.x * blockDim.x + threadIdx.x;
  if (i >= n4) return;
  f32x4 a = ((const f32x4*)out)[i];
  f32x4 b = ((const f32x4*)add)[i];
  ((f32x4*)out)[i] = a + b;
}

// ---------------- persistent GRU kernel ----------------
// grid = 128 blocks x 256 threads. blocks [0,64): fwd, [64,128): bwd.
// Each block owns 16 h-columns (ct) for all 32 batch rows; 4 waves split K.
// U hi/lo fragments live in registers (immune to per-step acquire cache-invalidates).

__global__ __launch_bounds__(256, 1)
void k_gru(const int* __restrict__ tokens,
           const unsigned char* __restrict__ maskp,
           const unsigned short* __restrict__ embb,
           const unsigned short* __restrict__ WF,
           const unsigned short* __restrict__ UFhi,
           const unsigned short* __restrict__ UFlo,
           const float* __restrict__ bin_f, const float* __restrict__ brec_f,
           const float* __restrict__ bin_b, const float* __restrict__ brec_b,
           uint32_t* __restrict__ hpack,   // [2 dir][2 buf][32][1024] u32 (hi16|lo16)
           uint32_t* flags,                // [2 dir][64]
           float* out_f, float* out_b, int atomic_out)
{
  const int blk  = blockIdx.x;
  const int d    = blk >> 6;
  const int ct   = blk & 63;
  const int tid  = threadIdx.x;
  const int lane = tid & 63;
  const int wave = tid >> 6;
  const int l15  = lane & 15;
  const int lg   = lane >> 4;
  const int mask_is32 = (maskp[1] == 0) ? 1 : 0;   // lengths>=128 => mask[0][1]==1 if byte-packed

  const float* bin  = d ? bin_b  : bin_f;
  const float* brec = d ? brec_b : brec_f;
  const int col = ct * 16 + l15;
  const float bz  = bin[col]          + brec[col];
  const float br  = bin[H_ + col]     + brec[H_ + col];
  const float bhx = bin[2 * H_ + col];
  const float bhu = brec[2 * H_ + col];

  // persistent weight fragments in registers: 3p*8ks*2(hi,lo)*4 + 3p*4ks*4 = 240 VGPR
  bf16x8 Uh[3][8], Ul[3][8], Wr[3][4];
  {
    const size_t bu = (size_t)(d * 64 + ct) * (3 * 32 * 64 * 8);
    #pragma unroll
    for (int p = 0; p < 3; ++p)
      #pragma unroll
      for (int ks = 0; ks < 8; ++ks){
        size_t off = bu + ((size_t)(p * 32 + (wave * 8 + ks)) * 64 + lane) * 8;
        Uh[p][ks] = *(const bf16x8*)(UFhi + off);
        Ul[p][ks] = *(const bf16x8*)(UFlo + off);
      }
    const size_t bw = (size_t)(d * 64 + ct) * (3 * 16 * 64 * 8);
    #pragma unroll
    for (int p = 0; p < 3; ++p)
      #pragma unroll
      for (int ks = 0; ks < 4; ++ks){
        size_t off = bw + ((size_t)(p * 16 + (wave * 4 + ks)) * 64 + lane) * 8;
        Wr[p][ks] = *(const bf16x8*)(WF + off);
      }
  }

  __shared__ f32x4 red[4][2][4][64];   // 32 KB: [wave][mtile][slot z,r,hx,hu][lane]

  uint32_t* hp  = hpack + (size_t)d * 2 * B_ * H_;
  uint32_t* flg = flags + d * 64;
  float* outp = atomic_out ? out_f : (d ? out_b : out_f);

  const f32x4 z4 = {0.f, 0.f, 0.f, 0.f};

  for (int t = 0; t < T_; ++t){
    // ---- wait until all 64 producer blocks of this direction finished step t-1
    if (t > 0){
      if (wave == 0){
        while (__hip_atomic_load(flg + lane, __ATOMIC_RELAXED, __HIP_MEMORY_SCOPE_AGENT) < (uint32_t)t)
          __builtin_amdgcn_s_sleep(1);
        __threadfence();   // acquire: invalidate stale h lines
      }
    }
    __syncthreads();

    const int te = d ? (T_ - 1 - t) : t;
    const uint32_t* hcur = hp + (size_t)(t & 1) * B_ * H_;
    uint32_t*       hnxt = hp + (size_t)((t + 1) & 1) * B_ * H_;

    const int tok0 = tokens[l15 * T_ + te];
    const int tok1 = tokens[(16 + l15) * T_ + te];

    f32x4 accz[2]  = {z4, z4};
    f32x4 accr[2]  = {z4, z4};
    f32x4 acchx[2] = {z4, z4};   // x-part of candidate gate (kept separate: r multiplies only uh)
    f32x4 acchu[2] = {z4, z4};   // U-part of candidate gate

    // on-the-fly input projection x@W (K=512 split over 4 waves), single bf16
    #pragma unroll
    for (int ks = 0; ks < 4; ++ks){
      const int koff = (wave * 4 + ks) * 32 + (lg << 3);
      bf16x8 xa0 = *(const bf16x8*)(embb + (size_t)tok0 * EMB_ + koff);
      bf16x8 xa1 = *(const bf16x8*)(embb + (size_t)tok1 * EMB_ + koff);
      accz[0]  = mfma16(xa0, Wr[0][ks], accz[0]);
      accz[1]  = mfma16(xa1, Wr[0][ks], accz[1]);
      accr[0]  = mfma16(xa0, Wr[1][ks], accr[0]);
      accr[1]  = mfma16(xa1, Wr[1][ks], accr[1]);
      acchx[0] = mfma16(xa0, Wr[2][ks], acchx[0]);
      acchx[1] = mfma16(xa1, Wr[2][ks], acchx[1]);
    }

    // recurrent path h@U (K=1024 split over 4 waves), split-bf16 (3 MFMA terms)
    #pragma unroll
    for (int ks = 0; ks < 8; ++ks){
      const int koff = (wave * 8 + ks) * 32 + (lg << 3);
      const u32x4* pa0 = (const u32x4*)(hcur + (size_t)l15 * H_ + koff);
      const u32x4* pa1 = (const u32x4*)(hcur + (size_t)(16 + l15) * H_ + koff);
      u32x4 a00 = pa0[0], a01 = pa0[1];
      u32x4 a10 = pa1[0], a11 = pa1[1];
      bf16x8 h0 = upk_hi(a00, a01), L0 = upk_lo(a00, a01);
      bf16x8 h1 = upk_hi(a10, a11), L1 = upk_lo(a10, a11);
      #pragma unroll
      for (int p = 0; p < 3; ++p){
        f32x4* acc = (p == 0) ? accz : (p == 1) ? accr : acchu;
        acc[0] = mfma16(h0, Uh[p][ks], acc[0]);
        acc[0] = mfma16(L0, Uh[p][ks], acc[0]);
        acc[0] = mfma16(h0, Ul[p][ks], acc[0]);
        acc[1] = mfma16(h1, Uh[p][ks], acc[1]);
        acc[1] = mfma16(L1, Uh[p][ks], acc[1]);
        acc[1] = mfma16(h1, Ul[p][ks], acc[1]);
      }
    }

    // cross-wave K-reduction
    red[wave][0][0][lane] = accz[0];  red[wave][0][1][lane] = accr[0];
    red[wave][0][2][lane] = acchx[0]; red[wave][0][3][lane] = acchu[0];
    red[wave][1][0][lane] = accz[1];  red[wave][1][1][lane] = accr[1];
    red[wave][1][2][lane] = acchx[1]; red[wave][1][3][lane] = acchu[1];
    __syncthreads();

    if (wave < 2){
      const int mt = wave;
      f32x4 rz  = red[0][mt][0][lane] + red[1][mt][0][lane] + red[2][mt][0][lane] + red[3][mt][0][lane];
      f32x4 rr  = red[0][mt][1][lane] + red[1][mt][1][lane] + red[2][mt][1][lane] + red[3][mt][1][lane];
      f32x4 rhx = red[0][mt][2][lane] + red[1][mt][2][lane] + red[2][mt][2][lane] + red[3][mt][2][lane];
      f32x4 rhu = red[0][mt][3][lane] + red[1][mt][3][lane] + red[2][mt][3][lane] + red[3][mt][3][lane];
      #pragma unroll
      for (int i = 0; i < 4; ++i){
        const int row = mt * 16 + (lg << 2) + i;          // C/D layout: col=lane&15, row=(lane>>4)*4+i
        const float z  = sigm(rz[i] + bz);
        const float r  = sigm(rr[i] + br);
        const float hh = tanh_f(rhx[i] + bhx + r * (rhu[i] + bhu));
        const uint32_t hpv = hcur[(size_t)row * H_ + col];
        const float hprev = bf2f(hpv >> 16) + bf2f(hpv & 0xFFFFu);
        const int midx = row * T_ + te;
        const bool m = mask_is32 ? (((const int*)maskp)[midx] != 0) : (maskp[midx] != 0);
        const float hn = m ? (z * hprev + (1.f - z) * hh) : hprev;
        const uint32_t hi = f2bf_rne_u(hn);
        const float lo = hn - bf2f(hi);
        hnxt[(size_t)row * H_ + col] = (hi << 16) | f2bf_rne_u(lo);
        const size_t oidx = ((size_t)row * T_ + te) * H_ + col;
        if (atomic_out) atomicAdd(outp + oidx, hn);
        else            outp[oidx] = hn;
      }
    }
    __syncthreads();   // drains all waves' global stores (compiler emits vmcnt(0))

    if (tid == 0){
      __threadfence();  // release: write back dirty L2 so other XCDs see h
      __hip_atomic_store(flg + ct, (uint32_t)(t + 1), __ATOMIC_RELEASE, __HIP_MEMORY_SCOPE_AGENT);
    }
  }
}

// ---------------- launch ----------------

extern "C" void kernel_launch(void* const* d_in, const int* in_sizes, int n_in,
                              void* d_out, int out_size, void* d_ws, size_t ws_size,
                              hipStream_t stream) {
  const int*   tokens = (const int*)d_in[0];
  const unsigned char* mask = (const unsigned char*)d_in[1];
  const float* emb   = (const float*)d_in[2];
  const float* Wf    = (const float*)d_in[3];
  const float* Uf    = (const float*)d_in[4];
  const float* bfin  = (const float*)d_in[5];
  const float* bfrec = (const float*)d_in[6];
  const float* Wb    = (const float*)d_in[7];
  const float* Ub    = (const float*)d_in[8];
  const float* bbin  = (const float*)d_in[9];
  const float* bbrec = (const float*)d_in[10];
  float* out = (float*)d_out;
  char*  ws  = (char*)d_ws;

  // workspace layout (bytes)
  const size_t o_embb  = 0;                         // 32000*512*2      = 32,768,000
  const size_t o_wf    = 32768000;                  // 2*64*3*16*64*8*2 =  6,291,456
  const size_t o_ufhi  = 39059456;                  // 2*64*3*32*64*8*2 = 12,582,912
  const size_t o_uflo  = 51642368;                  // 12,582,912
  const size_t o_hpack = 64225280;                  // 2*2*32*1024*4    =    524,288
  const size_t o_flags = 64749568;                  // 512
  const size_t o_bwd   = 64750080;                  // 32*512*1024*4    = 67,108,864
  const size_t need_full = o_bwd + 67108864;

  const int atomic_mode = (ws_size < need_full) ? 1 : 0;

  // reset h double-buffers + flags every call (harness does not re-poison between replays)
  hipMemsetAsync(ws + o_hpack, 0, 524288 + 512, stream);

  k_emb2bf<<<8000, 256, 0, stream>>>(emb, (unsigned short*)(ws + o_embb), 2048000);
  k_packW <<<1536, 256, 0, stream>>>(Wf, Wb, (unsigned short*)(ws + o_wf));
  k_packU <<<3072, 256, 0, stream>>>(Uf, Ub, (unsigned short*)(ws + o_ufhi),
                                             (unsigned short*)(ws + o_uflo));
  if (atomic_mode)
    hipMemsetAsync(out, 0, (size_t)out_size * sizeof(float), stream);

  k_gru<<<128, 256, 0, stream>>>(tokens, mask,
                                 (const unsigned short*)(ws + o_embb),
                                 (const unsigned short*)(ws + o_wf),
                                 (const unsigned short*)(ws + o_ufhi),
                                 (const unsigned short*)(ws + o_uflo),
                                 bfin, bfrec, bbin, bbrec,
                                 (uint32_t*)(ws + o_hpack),
                                 (uint32_t*)(ws + o_flags),
                                 out, (float*)(ws + o_bwd), atomic_mode);

  if (!atomic_mode)
    k_add<<<16384, 256, 0, stream>>>(out, (const float*)(ws + o_bwd), 4194304);
}

// Round 2
// 6519.331 us; speedup vs baseline: 1.4002x; 1.4002x over previous
//
#include <hip/hip_runtime.h>
#include <stdint.h>

#define B_    32
#define T_    512
#define H_    1024
#define H3_   3072
#define EMB_  512

typedef __bf16   bf16x8 __attribute__((ext_vector_type(8)));
typedef float    f32x4  __attribute__((ext_vector_type(4)));
typedef uint32_t u32x4  __attribute__((ext_vector_type(4)));

__device__ __forceinline__ uint32_t f2bf_rne_u(float x){
  union { float f; uint32_t u; } v; v.f = x;
  uint32_t u = v.u;
  return (u + 0x7FFFu + ((u >> 16) & 1u)) >> 16;
}
__device__ __forceinline__ float bf2f(uint32_t h16){
  union { uint32_t u; float f; } v; v.u = h16 << 16; return v.f;
}
__device__ __forceinline__ float sigm(float x){ return 1.f / (1.f + __expf(-x)); }
__device__ __forceinline__ float tanh_f(float x){ float e = __expf(2.f * x); return 1.f - 2.f / (e + 1.f); }

__device__ __forceinline__ f32x4 mfma16(bf16x8 a, bf16x8 b, f32x4 c){
  return __builtin_amdgcn_mfma_f32_16x16x32_bf16(a, b, c, 0, 0, 0);
}

// 4 u64 (each = 2 packed u32 words, word = hi16|lo16) -> hi-halves / lo-halves bf16x8
__device__ __forceinline__ void upk64(const uint64_t* e, bf16x8& hi, bf16x8& lo){
  uint32_t w0 = (uint32_t)e[0], w1 = (uint32_t)(e[0] >> 32);
  uint32_t w2 = (uint32_t)e[1], w3 = (uint32_t)(e[1] >> 32);
  uint32_t w4 = (uint32_t)e[2], w5 = (uint32_t)(e[2] >> 32);
  uint32_t w6 = (uint32_t)e[3], w7 = (uint32_t)(e[3] >> 32);
  u32x4 h, l;
  h.x = (w0 >> 16) | (w1 & 0xFFFF0000u);
  h.y = (w2 >> 16) | (w3 & 0xFFFF0000u);
  h.z = (w4 >> 16) | (w5 & 0xFFFF0000u);
  h.w = (w6 >> 16) | (w7 & 0xFFFF0000u);
  l.x = (w0 & 0xFFFFu) | (w1 << 16);
  l.y = (w2 & 0xFFFFu) | (w3 << 16);
  l.z = (w4 & 0xFFFFu) | (w5 << 16);
  l.w = (w6 & 0xFFFFu) | (w7 << 16);
  hi = __builtin_bit_cast(bf16x8, h);
  lo = __builtin_bit_cast(bf16x8, l);
}

// ---------------- prep kernels ----------------

__global__ void k_emb2bf(const float* __restrict__ src, unsigned short* __restrict__ dst, int n8){
  int i = blockIdx.x * blockDim.x + threadIdx.x;
  if (i >= n8) return;
  const float4* s = (const float4*)src + (size_t)i * 2;
  float4 x = s[0], y = s[1];
  u32x4 o;
  o.x = f2bf_rne_u(x.x) | (f2bf_rne_u(x.y) << 16);
  o.y = f2bf_rne_u(x.z) | (f2bf_rne_u(x.w) << 16);
  o.z = f2bf_rne_u(y.x) | (f2bf_rne_u(y.y) << 16);
  o.w = f2bf_rne_u(y.z) | (f2bf_rne_u(y.w) << 16);
  ((u32x4*)dst)[i] = o;
}

// W (EMB x 3H) -> MFMA B-fragment layout [d][ct(64)][p(3)][ks(16)][lane(64)][8], bf16
__global__ void k_packW(const float* __restrict__ Wf, const float* __restrict__ Wb,
                        unsigned short* __restrict__ out){
  int idx = blockIdx.x * 256 + threadIdx.x;            // 2*64*3*16*64 = 393216
  int lane = idx & 63;
  int ks   = (idx >> 6) & 15;
  int rest = idx >> 10;                                 // d*192 + ct*3 + p
  int p  = rest % 3;
  int ct = (rest / 3) & 63;
  int d  = rest / 192;
  const float* W = d ? Wb : Wf;
  int colg = p * 1024 + ct * 16 + (lane & 15);
  int k0   = ks * 32 + ((lane >> 4) << 3);
  unsigned short* o = out + (size_t)idx * 8;
  #pragma unroll
  for (int b = 0; b < 8; ++b)
    o[b] = (unsigned short)f2bf_rne_u(W[(size_t)(k0 + b) * H3_ + colg]);
}

// U (H x 3H) -> hi/lo split fragment layout [d][ct][p][ks(32)][lane][8]
__global__ void k_packU(const float* __restrict__ Uf, const float* __restrict__ Ub,
                        unsigned short* __restrict__ ohi, unsigned short* __restrict__ olo){
  int idx = blockIdx.x * 256 + threadIdx.x;            // 2*64*3*32*64 = 786432
  int lane = idx & 63;
  int ks   = (idx >> 6) & 31;
  int rest = idx >> 11;                                 // d*192 + ct*3 + p
  int p  = rest % 3;
  int ct = (rest / 3) & 63;
  int d  = rest / 192;
  const float* U = d ? Ub : Uf;
  int colg = p * 1024 + ct * 16 + (lane & 15);
  int k0   = ks * 32 + ((lane >> 4) << 3);
  size_t o = (size_t)idx * 8;
  #pragma unroll
  for (int b = 0; b < 8; ++b){
    float u = U[(size_t)(k0 + b) * H3_ + colg];
    uint32_t hi = f2bf_rne_u(u);
    float lo = u - bf2f(hi);
    ohi[o + b] = (unsigned short)hi;
    olo[o + b] = (unsigned short)f2bf_rne_u(lo);
  }
}

__global__ void k_add(float* __restrict__ out, const float* __restrict__ add, int n4){
  int i = blockIdx.x * blockDim.x + threadIdx.x;
  if (i >= n4) return;
  f32x4 a = ((const f32x4*)out)[i];
  f32x4 b = ((const f32x4*)add)[i];
  ((f32x4*)out)[i] = a + b;
}

// ---------------- persistent GRU kernel ----------------
// grid = 128 blocks x 256 threads. blocks [0,64): fwd, [64,128): bwd.
// Each block owns 16 h-columns for all 32 batch rows; 4 waves split K.
// NO cache-maintenance fences: h + flags use relaxed agent-scope atomics
// (sc0 sc1 -> L3, the cross-XCD coherence point). Ordering = vmcnt(0) drain
// before block barrier, flag store after. L2 stays valid across steps.

__global__ __launch_bounds__(256, 1)
void k_gru(const int* __restrict__ tokens,
           const unsigned char* __restrict__ maskp,
           const unsigned short* __restrict__ embb,
           const unsigned short* __restrict__ WF,
           const unsigned short* __restrict__ UFhi,
           const unsigned short* __restrict__ UFlo,
           const float* __restrict__ bin_f, const float* __restrict__ brec_f,
           const float* __restrict__ bin_b, const float* __restrict__ brec_b,
           uint32_t* __restrict__ hpack,   // [2 dir][2 buf][32][1024] u32 (hi16|lo16)
           uint32_t* flags,                // [2 dir][64]
           float* out_f, float* out_b, int atomic_out)
{
  const int blk  = blockIdx.x;
  const int d    = blk >> 6;
  const int ct   = blk & 63;
  const int tid  = threadIdx.x;
  const int lane = tid & 63;
  const int wave = tid >> 6;
  const int l15  = lane & 15;
  const int lg   = lane >> 4;
  const int mask_is32 = (maskp[1] == 0) ? 1 : 0;   // lengths>=128 => mask[0][1]==1 if byte-packed

  const float* bin  = d ? bin_b  : bin_f;
  const float* brec = d ? brec_b : brec_f;
  const int col = ct * 16 + l15;
  const float bz  = bin[col]          + brec[col];
  const float br  = bin[H_ + col]     + brec[H_ + col];
  const float bhx = bin[2 * H_ + col];
  const float bhu = brec[2 * H_ + col];

  // persistent weight fragments in registers
  bf16x8 Uh[3][8], Ul[3][8], Wr[3][4];
  {
    const size_t bu = (size_t)(d * 64 + ct) * (3 * 32 * 64 * 8);
    #pragma unroll
    for (int p = 0; p < 3; ++p)
      #pragma unroll
      for (int ks = 0; ks < 8; ++ks){
        size_t off = bu + ((size_t)(p * 32 + (wave * 8 + ks)) * 64 + lane) * 8;
        Uh[p][ks] = *(const bf16x8*)(UFhi + off);
        Ul[p][ks] = *(const bf16x8*)(UFlo + off);
      }
    const size_t bw = (size_t)(d * 64 + ct) * (3 * 16 * 64 * 8);
    #pragma unroll
    for (int p = 0; p < 3; ++p)
      #pragma unroll
      for (int ks = 0; ks < 4; ++ks){
        size_t off = bw + ((size_t)(p * 16 + (wave * 4 + ks)) * 64 + lane) * 8;
        Wr[p][ks] = *(const bf16x8*)(WF + off);
      }
  }

  __shared__ f32x4 red[4][2][4][64];   // 32 KB: [wave][mtile][slot z,r,hx,hu][lane]

  uint32_t* hp  = hpack + (size_t)d * 2 * B_ * H_;
  uint32_t* flg = flags + d * 64;
  float* outp = atomic_out ? out_f : (d ? out_b : out_f);

  const f32x4 z4 = {0.f, 0.f, 0.f, 0.f};
  float hreg[4] = {0.f, 0.f, 0.f, 0.f};   // this block's own h columns (waves 0,1)

  for (int t = 0; t < T_; ++t){
    const int te = d ? (T_ - 1 - t) : t;
    const uint32_t* hcur = hp + (size_t)(t & 1) * B_ * H_;
    uint32_t*       hnxt = hp + (size_t)((t + 1) & 1) * B_ * H_;

    const int tok0 = tokens[l15 * T_ + te];
    const int tok1 = tokens[(16 + l15) * T_ + te];

    f32x4 accz[2]  = {z4, z4};
    f32x4 accr[2]  = {z4, z4};
    f32x4 acchx[2] = {z4, z4};   // x-part of candidate gate
    f32x4 acchu[2] = {z4, z4};   // U-part of candidate gate

    // ---- input projection x@W: independent of h -> do it BEFORE the wait
    #pragma unroll
    for (int ks = 0; ks < 4; ++ks){
      const int koff = (wave * 4 + ks) * 32 + (lg << 3);
      bf16x8 xa0 = *(const bf16x8*)(embb + (size_t)tok0 * EMB_ + koff);
      bf16x8 xa1 = *(const bf16x8*)(embb + (size_t)tok1 * EMB_ + koff);
      accz[0]  = mfma16(xa0, Wr[0][ks], accz[0]);
      accz[1]  = mfma16(xa1, Wr[0][ks], accz[1]);
      accr[0]  = mfma16(xa0, Wr[1][ks], accr[0]);
      accr[1]  = mfma16(xa1, Wr[1][ks], accr[1]);
      acchx[0] = mfma16(xa0, Wr[2][ks], acchx[0]);
      acchx[1] = mfma16(xa1, Wr[2][ks], acchx[1]);
    }

    // ---- wait until all 64 producer blocks of this direction posted step t
    if (t > 0){
      if (wave == 0){
        while (__hip_atomic_load(flg + lane, __ATOMIC_RELAXED, __HIP_MEMORY_SCOPE_AGENT) < (uint32_t)t)
          __builtin_amdgcn_s_sleep(1);
      }
      __syncthreads();
    }

    // ---- recurrent path h@U, coherent (L3) loads in 2 bursts of 16x u64
    #pragma unroll
    for (int half = 0; half < 2; ++half){
      uint64_t e[32];
      #pragma unroll
      for (int ks2 = 0; ks2 < 4; ++ks2){
        const int ks = half * 4 + ks2;
        const int koff = (wave * 8 + ks) * 32 + (lg << 3);
        const uint64_t* pa0 = (const uint64_t*)(hcur + (size_t)l15 * H_ + koff);
        const uint64_t* pa1 = (const uint64_t*)(hcur + (size_t)(16 + l15) * H_ + koff);
        #pragma unroll
        for (int j = 0; j < 4; ++j){
          e[ks2 * 8 + j]     = __hip_atomic_load(pa0 + j, __ATOMIC_RELAXED, __HIP_MEMORY_SCOPE_AGENT);
          e[ks2 * 8 + 4 + j] = __hip_atomic_load(pa1 + j, __ATOMIC_RELAXED, __HIP_MEMORY_SCOPE_AGENT);
        }
      }
      #pragma unroll
      for (int ks2 = 0; ks2 < 4; ++ks2){
        const int ks = half * 4 + ks2;
        bf16x8 h0, L0, h1, L1;
        upk64(&e[ks2 * 8],     h0, L0);
        upk64(&e[ks2 * 8 + 4], h1, L1);
        #pragma unroll
        for (int p = 0; p < 3; ++p){
          f32x4* acc = (p == 0) ? accz : (p == 1) ? accr : acchu;
          acc[0] = mfma16(h0, Uh[p][ks], acc[0]);
          acc[0] = mfma16(L0, Uh[p][ks], acc[0]);
          acc[0] = mfma16(h0, Ul[p][ks], acc[0]);
          acc[1] = mfma16(h1, Uh[p][ks], acc[1]);
          acc[1] = mfma16(L1, Uh[p][ks], acc[1]);
          acc[1] = mfma16(h1, Ul[p][ks], acc[1]);
        }
      }
    }

    // ---- cross-wave K-reduction
    red[wave][0][0][lane] = accz[0];  red[wave][0][1][lane] = accr[0];
    red[wave][0][2][lane] = acchx[0]; red[wave][0][3][lane] = acchu[0];
    red[wave][1][0][lane] = accz[1];  red[wave][1][1][lane] = accr[1];
    red[wave][1][2][lane] = acchx[1]; red[wave][1][3][lane] = acchu[1];
    __syncthreads();

    if (wave < 2){
      const int mt = wave;
      f32x4 rz  = red[0][mt][0][lane] + red[1][mt][0][lane] + red[2][mt][0][lane] + red[3][mt][0][lane];
      f32x4 rr  = red[0][mt][1][lane] + red[1][mt][1][lane] + red[2][mt][1][lane] + red[3][mt][1][lane];
      f32x4 rhx = red[0][mt][2][lane] + red[1][mt][2][lane] + red[2][mt][2][lane] + red[3][mt][2][lane];
      f32x4 rhu = red[0][mt][3][lane] + red[1][mt][3][lane] + red[2][mt][3][lane] + red[3][mt][3][lane];
      #pragma unroll
      for (int i = 0; i < 4; ++i){
        const int row = mt * 16 + (lg << 2) + i;          // C/D layout: col=lane&15, row=(lane>>4)*4+i
        const float z  = sigm(rz[i] + bz);
        const float r  = sigm(rr[i] + br);
        const float hh = tanh_f(rhx[i] + bhx + r * (rhu[i] + bhu));
        const float hprev = hreg[i];                       // own column, kept in registers
        const int midx = row * T_ + te;
        const bool m = mask_is32 ? (((const int*)maskp)[midx] != 0) : (maskp[midx] != 0);
        const float hn = m ? (z * hprev + (1.f - z) * hh) : hprev;
        hreg[i] = hn;
        const uint32_t hi = f2bf_rne_u(hn);
        const float lo = hn - bf2f(hi);
        __hip_atomic_store(hnxt + (size_t)row * H_ + col, (hi << 16) | f2bf_rne_u(lo),
                           __ATOMIC_RELAXED, __HIP_MEMORY_SCOPE_AGENT);
        const size_t oidx = ((size_t)row * T_ + te) * H_ + col;
        if (atomic_out) atomicAdd(outp + oidx, hn);
        else            outp[oidx] = hn;
      }
      // drain own h stores to the coherence point before signaling
      asm volatile("s_waitcnt vmcnt(0)" ::: "memory");
    }
    __syncthreads();

    if (tid == 0)
      __hip_atomic_store(flg + ct, (uint32_t)(t + 1), __ATOMIC_RELAXED, __HIP_MEMORY_SCOPE_AGENT);
  }
}

// ---------------- launch ----------------

extern "C" void kernel_launch(void* const* d_in, const int* in_sizes, int n_in,
                              void* d_out, int out_size, void* d_ws, size_t ws_size,
                              hipStream_t stream) {
  const int*   tokens = (const int*)d_in[0];
  const unsigned char* mask = (const unsigned char*)d_in[1];
  const float* emb   = (const float*)d_in[2];
  const float* Wf    = (const float*)d_in[3];
  const float* Uf    = (const float*)d_in[4];
  const float* bfin  = (const float*)d_in[5];
  const float* bfrec = (const float*)d_in[6];
  const float* Wb    = (const float*)d_in[7];
  const float* Ub    = (const float*)d_in[8];
  const float* bbin  = (const float*)d_in[9];
  const float* bbrec = (const float*)d_in[10];
  float* out = (float*)d_out;
  char*  ws  = (char*)d_ws;

  // workspace layout (bytes)
  const size_t o_embb  = 0;                         // 32000*512*2      = 32,768,000
  const size_t o_wf    = 32768000;                  // 2*64*3*16*64*8*2 =  6,291,456
  const size_t o_ufhi  = 39059456;                  // 2*64*3*32*64*8*2 = 12,582,912
  const size_t o_uflo  = 51642368;                  // 12,582,912
  const size_t o_hpack = 64225280;                  // 2*2*32*1024*4    =    524,288
  const size_t o_flags = 64749568;                  // 512
  const size_t o_bwd   = 64750080;                  // 32*512*1024*4    = 67,108,864
  const size_t need_full = o_bwd + 67108864;

  const int atomic_mode = (ws_size < need_full) ? 1 : 0;

  // reset h double-buffers + flags every call (harness does not re-poison between replays)
  hipMemsetAsync(ws + o_hpack, 0, 524288 + 512, stream);

  k_emb2bf<<<8000, 256, 0, stream>>>(emb, (unsigned short*)(ws + o_embb), 2048000);
  k_packW <<<1536, 256, 0, stream>>>(Wf, Wb, (unsigned short*)(ws + o_wf));
  k_packU <<<3072, 256, 0, stream>>>(Uf, Ub, (unsigned short*)(ws + o_ufhi),
                                             (unsigned short*)(ws + o_uflo));
  if (atomic_mode)
    hipMemsetAsync(out, 0, (size_t)out_size * sizeof(float), stream);

  k_gru<<<128, 256, 0, stream>>>(tokens, mask,
                                 (const unsigned short*)(ws + o_embb),
                                 (const unsigned short*)(ws + o_wf),
                                 (const unsigned short*)(ws + o_ufhi),
                                 (const unsigned short*)(ws + o_uflo),
                                 bfin, bfrec, bbin, bbrec,
                                 (uint32_t*)(ws + o_hpack),
                                 (uint32_t*)(ws + o_flags),
                                 out, (float*)(ws + o_bwd), atomic_mode);

  if (!atomic_mode)
    k_add<<<16384, 256, 0, stream>>>(out, (const float*)(ws + o_bwd), 4194304);
}

// Round 3
// 5850.206 us; speedup vs baseline: 1.5603x; 1.1144x over previous
//
#include <hip/hip_runtime.h>
#include <stdint.h>

#define B_    32
#define T_    512
#define H_    1024
#define H3_   3072
#define EMB_  512

typedef __bf16   bf16x8 __attribute__((ext_vector_type(8)));
typedef float    f32x4  __attribute__((ext_vector_type(4)));
typedef uint32_t u32x4  __attribute__((ext_vector_type(4)));

__device__ __forceinline__ uint32_t f2bf_rne_u(float x){
  union { float f; uint32_t u; } v; v.f = x;
  uint32_t u = v.u;
  return (u + 0x7FFFu + ((u >> 16) & 1u)) >> 16;
}
__device__ __forceinline__ float bf2f(uint32_t h16){
  union { uint32_t u; float f; } v; v.u = h16 << 16; return v.f;
}
__device__ __forceinline__ float sigm(float x){ return 1.f / (1.f + __expf(-x)); }
__device__ __forceinline__ float tanh_f(float x){ float e = __expf(2.f * x); return 1.f - 2.f / (e + 1.f); }

__device__ __forceinline__ f32x4 mfma16(bf16x8 a, bf16x8 b, f32x4 c){
  return __builtin_amdgcn_mfma_f32_16x16x32_bf16(a, b, c, 0, 0, 0);
}

// 4 u64 (each = 2 packed u32 words, word = hi16|lo16) -> hi-halves / lo-halves bf16x8
__device__ __forceinline__ void upk64(const uint64_t* e, bf16x8& hi, bf16x8& lo){
  uint32_t w0 = (uint32_t)e[0], w1 = (uint32_t)(e[0] >> 32);
  uint32_t w2 = (uint32_t)e[1], w3 = (uint32_t)(e[1] >> 32);
  uint32_t w4 = (uint32_t)e[2], w5 = (uint32_t)(e[2] >> 32);
  uint32_t w6 = (uint32_t)e[3], w7 = (uint32_t)(e[3] >> 32);
  u32x4 h, l;
  h.x = (w0 >> 16) | (w1 & 0xFFFF0000u);
  h.y = (w2 >> 16) | (w3 & 0xFFFF0000u);
  h.z = (w4 >> 16) | (w5 & 0xFFFF0000u);
  h.w = (w6 >> 16) | (w7 & 0xFFFF0000u);
  l.x = (w0 & 0xFFFFu) | (w1 << 16);
  l.y = (w2 & 0xFFFFu) | (w3 << 16);
  l.z = (w4 & 0xFFFFu) | (w5 << 16);
  l.w = (w6 & 0xFFFFu) | (w7 << 16);
  hi = __builtin_bit_cast(bf16x8, h);
  lo = __builtin_bit_cast(bf16x8, l);
}

// ---------------- prep kernels ----------------

__global__ void k_emb2bf(const float* __restrict__ src, unsigned short* __restrict__ dst, int n8){
  int i = blockIdx.x * blockDim.x + threadIdx.x;
  if (i >= n8) return;
  const float4* s = (const float4*)src + (size_t)i * 2;
  float4 x = s[0], y = s[1];
  u32x4 o;
  o.x = f2bf_rne_u(x.x) | (f2bf_rne_u(x.y) << 16);
  o.y = f2bf_rne_u(x.z) | (f2bf_rne_u(x.w) << 16);
  o.z = f2bf_rne_u(y.x) | (f2bf_rne_u(y.y) << 16);
  o.w = f2bf_rne_u(y.z) | (f2bf_rne_u(y.w) << 16);
  ((u32x4*)dst)[i] = o;
}

// W (EMB x 3H) -> MFMA B-fragment layout [d][ct(64)][p(3)][ks(16)][lane(64)][8], bf16
__global__ void k_packW(const float* __restrict__ Wf, const float* __restrict__ Wb,
                        unsigned short* __restrict__ out){
  int idx = blockIdx.x * 256 + threadIdx.x;            // 2*64*3*16*64 = 393216
  int lane = idx & 63;
  int ks   = (idx >> 6) & 15;
  int rest = idx >> 10;                                 // d*192 + ct*3 + p
  int p  = rest % 3;
  int ct = (rest / 3) & 63;
  int d  = rest / 192;
  const float* W = d ? Wb : Wf;
  int colg = p * 1024 + ct * 16 + (lane & 15);
  int k0   = ks * 32 + ((lane >> 4) << 3);
  unsigned short* o = out + (size_t)idx * 8;
  #pragma unroll
  for (int b = 0; b < 8; ++b)
    o[b] = (unsigned short)f2bf_rne_u(W[(size_t)(k0 + b) * H3_ + colg]);
}

// U (H x 3H) -> hi/lo split fragment layout [d][ct][p][ks(32)][lane][8]
__global__ void k_packU(const float* __restrict__ Uf, const float* __restrict__ Ub,
                        unsigned short* __restrict__ ohi, unsigned short* __restrict__ olo){
  int idx = blockIdx.x * 256 + threadIdx.x;            // 2*64*3*32*64 = 786432
  int lane = idx & 63;
  int ks   = (idx >> 6) & 31;
  int rest = idx >> 11;                                 // d*192 + ct*3 + p
  int p  = rest % 3;
  int ct = (rest / 3) & 63;
  int d  = rest / 192;
  const float* U = d ? Ub : Uf;
  int colg = p * 1024 + ct * 16 + (lane & 15);
  int k0   = ks * 32 + ((lane >> 4) << 3);
  size_t o = (size_t)idx * 8;
  #pragma unroll
  for (int b = 0; b < 8; ++b){
    float u = U[(size_t)(k0 + b) * H3_ + colg];
    uint32_t hi = f2bf_rne_u(u);
    float lo = u - bf2f(hi);
    ohi[o + b] = (unsigned short)hi;
    olo[o + b] = (unsigned short)f2bf_rne_u(lo);
  }
}

__global__ void k_add(float* __restrict__ out, const float* __restrict__ add, int n4){
  int i = blockIdx.x * blockDim.x + threadIdx.x;
  if (i >= n4) return;
  f32x4 a = ((const f32x4*)out)[i];
  f32x4 b = ((const f32x4*)add)[i];
  ((f32x4*)out)[i] = a + b;
}

// ---------------- persistent GRU kernel ----------------
// grid = 128 blocks x 256 threads. blocks [0,64): fwd, [64,128): bwd.
// Each block owns 16 h-columns for all 32 batch rows; 4 waves split K.
// Signaling: 4 arrival counters per direction (one cacheline apart), each fed
// by 16 blocks' fire-and-forget atomicAdd after a vmcnt(0) drain of the h
// stores. Consumers poll with 4 lanes per block (sc1 loads -> L3), sleep(2).
// Out-stores are issued AFTER the signal: their HBM ack latency moves off the
// serial chain into the next step's wait phase.

__global__ __launch_bounds__(256, 1)
void k_gru(const int* __restrict__ tokens,
           const unsigned char* __restrict__ maskp,
           const unsigned short* __restrict__ embb,
           const unsigned short* __restrict__ WF,
           const unsigned short* __restrict__ UFhi,
           const unsigned short* __restrict__ UFlo,
           const float* __restrict__ bin_f, const float* __restrict__ brec_f,
           const float* __restrict__ bin_b, const float* __restrict__ brec_b,
           uint32_t* __restrict__ hpack,   // [2 dir][2 buf][32][1024] u32 (hi16|lo16)
           uint32_t* flags,                // [2 dir][4 lines x 32 dwords]
           float* out_f, float* out_b, int atomic_out)
{
  const int blk  = blockIdx.x;
  const int d    = blk >> 6;
  const int ct   = blk & 63;
  const int tid  = threadIdx.x;
  const int lane = tid & 63;
  const int wave = tid >> 6;
  const int l15  = lane & 15;
  const int lg   = lane >> 4;
  const int mask_is32 = (maskp[1] == 0) ? 1 : 0;   // lengths>=128 => mask[0][1]==1 if byte-packed

  const float* bin  = d ? bin_b  : bin_f;
  const float* brec = d ? brec_b : brec_f;
  const int col = ct * 16 + l15;
  const float bz  = bin[col]          + brec[col];
  const float br  = bin[H_ + col]     + brec[H_ + col];
  const float bhx = bin[2 * H_ + col];
  const float bhu = brec[2 * H_ + col];

  // persistent weight fragments in registers
  bf16x8 Uh[3][8], Ul[3][8], Wr[3][4];
  {
    const size_t bu = (size_t)(d * 64 + ct) * (3 * 32 * 64 * 8);
    #pragma unroll
    for (int p = 0; p < 3; ++p)
      #pragma unroll
      for (int ks = 0; ks < 8; ++ks){
        size_t off = bu + ((size_t)(p * 32 + (wave * 8 + ks)) * 64 + lane) * 8;
        Uh[p][ks] = *(const bf16x8*)(UFhi + off);
        Ul[p][ks] = *(const bf16x8*)(UFlo + off);
      }
    const size_t bw = (size_t)(d * 64 + ct) * (3 * 16 * 64 * 8);
    #pragma unroll
    for (int p = 0; p < 3; ++p)
      #pragma unroll
      for (int ks = 0; ks < 4; ++ks){
        size_t off = bw + ((size_t)(p * 16 + (wave * 4 + ks)) * 64 + lane) * 8;
        Wr[p][ks] = *(const bf16x8*)(WF + off);
      }
  }

  __shared__ f32x4 red[4][2][4][64];   // 32 KB: [wave][mtile][slot z,r,hx,hu][lane]

  uint32_t* hp  = hpack + (size_t)d * 2 * B_ * H_;
  uint32_t* cnt = flags + d * 128;                 // 4 counters, 128 B apart
  float* outp = atomic_out ? out_f : (d ? out_b : out_f);

  const f32x4 z4 = {0.f, 0.f, 0.f, 0.f};
  float hreg[4] = {0.f, 0.f, 0.f, 0.f};   // this block's own h columns (waves 0,1)

  for (int t = 0; t < T_; ++t){
    const int te = d ? (T_ - 1 - t) : t;
    const uint32_t* hcur = hp + (size_t)(t & 1) * B_ * H_;
    uint32_t*       hnxt = hp + (size_t)((t + 1) & 1) * B_ * H_;

    const int tok0 = tokens[l15 * T_ + te];
    const int tok1 = tokens[(16 + l15) * T_ + te];

    // prefetch mask bytes for the epilogue (off the critical tail)
    bool mb[4] = {false, false, false, false};
    if (wave < 2){
      #pragma unroll
      for (int i = 0; i < 4; ++i){
        const int row = wave * 16 + (lg << 2) + i;
        const int midx = row * T_ + te;
        mb[i] = mask_is32 ? (((const int*)maskp)[midx] != 0) : (maskp[midx] != 0);
      }
    }

    f32x4 accz[2]  = {z4, z4};
    f32x4 accr[2]  = {z4, z4};
    f32x4 acchx[2] = {z4, z4};   // x-part of candidate gate
    f32x4 acchu[2] = {z4, z4};   // U-part of candidate gate

    // ---- input projection x@W: independent of h -> do it BEFORE the wait
    #pragma unroll
    for (int ks = 0; ks < 4; ++ks){
      const int koff = (wave * 4 + ks) * 32 + (lg << 3);
      bf16x8 xa0 = *(const bf16x8*)(embb + (size_t)tok0 * EMB_ + koff);
      bf16x8 xa1 = *(const bf16x8*)(embb + (size_t)tok1 * EMB_ + koff);
      accz[0]  = mfma16(xa0, Wr[0][ks], accz[0]);
      accz[1]  = mfma16(xa1, Wr[0][ks], accz[1]);
      accr[0]  = mfma16(xa0, Wr[1][ks], accr[0]);
      accr[1]  = mfma16(xa1, Wr[1][ks], accr[1]);
      acchx[0] = mfma16(xa0, Wr[2][ks], acchx[0]);
      acchx[1] = mfma16(xa1, Wr[2][ks], acchx[1]);
    }

    // ---- wait until all 64 producer blocks of this direction posted step t
    if (t > 0){
      if (wave == 0 && lane < 4){
        const uint32_t tgt = (uint32_t)(16 * t);
        while (__hip_atomic_load(cnt + lane * 32, __ATOMIC_RELAXED, __HIP_MEMORY_SCOPE_AGENT) < tgt)
          __builtin_amdgcn_s_sleep(2);
      }
      __syncthreads();
    }

    // ---- recurrent path h@U, coherent (L3) loads in 2 bursts of 16x u64
    #pragma unroll
    for (int half = 0; half < 2; ++half){
      uint64_t e[32];
      #pragma unroll
      for (int ks2 = 0; ks2 < 4; ++ks2){
        const int ks = half * 4 + ks2;
        const int koff = (wave * 8 + ks) * 32 + (lg << 3);
        const uint64_t* pa0 = (const uint64_t*)(hcur + (size_t)l15 * H_ + koff);
        const uint64_t* pa1 = (const uint64_t*)(hcur + (size_t)(16 + l15) * H_ + koff);
        #pragma unroll
        for (int j = 0; j < 4; ++j){
          e[ks2 * 8 + j]     = __hip_atomic_load(pa0 + j, __ATOMIC_RELAXED, __HIP_MEMORY_SCOPE_AGENT);
          e[ks2 * 8 + 4 + j] = __hip_atomic_load(pa1 + j, __ATOMIC_RELAXED, __HIP_MEMORY_SCOPE_AGENT);
        }
      }
      #pragma unroll
      for (int ks2 = 0; ks2 < 4; ++ks2){
        const int ks = half * 4 + ks2;
        bf16x8 h0, L0, h1, L1;
        upk64(&e[ks2 * 8],     h0, L0);
        upk64(&e[ks2 * 8 + 4], h1, L1);
        #pragma unroll
        for (int p = 0; p < 3; ++p){
          f32x4* acc = (p == 0) ? accz : (p == 1) ? accr : acchu;
          acc[0] = mfma16(h0, Uh[p][ks], acc[0]);
          acc[0] = mfma16(L0, Uh[p][ks], acc[0]);
          acc[0] = mfma16(h0, Ul[p][ks], acc[0]);
          acc[1] = mfma16(h1, Uh[p][ks], acc[1]);
          acc[1] = mfma16(L1, Uh[p][ks], acc[1]);
          acc[1] = mfma16(h1, Ul[p][ks], acc[1]);
        }
      }
    }

    // ---- cross-wave K-reduction
    red[wave][0][0][lane] = accz[0];  red[wave][0][1][lane] = accr[0];
    red[wave][0][2][lane] = acchx[0]; red[wave][0][3][lane] = acchu[0];
    red[wave][1][0][lane] = accz[1];  red[wave][1][1][lane] = accr[1];
    red[wave][1][2][lane] = acchx[1]; red[wave][1][3][lane] = acchu[1];
    __syncthreads();

    float hn[4];
    if (wave < 2){
      const int mt = wave;
      f32x4 rz  = red[0][mt][0][lane] + red[1][mt][0][lane] + red[2][mt][0][lane] + red[3][mt][0][lane];
      f32x4 rr  = red[0][mt][1][lane] + red[1][mt][1][lane] + red[2][mt][1][lane] + red[3][mt][1][lane];
      f32x4 rhx = red[0][mt][2][lane] + red[1][mt][2][lane] + red[2][mt][2][lane] + red[3][mt][2][lane];
      f32x4 rhu = red[0][mt][3][lane] + red[1][mt][3][lane] + red[2][mt][3][lane] + red[3][mt][3][lane];
      #pragma unroll
      for (int i = 0; i < 4; ++i){
        const int row = mt * 16 + (lg << 2) + i;          // C/D layout: col=lane&15, row=(lane>>4)*4+i
        const float z  = sigm(rz[i] + bz);
        const float r  = sigm(rr[i] + br);
        const float hh = tanh_f(rhx[i] + bhx + r * (rhu[i] + bhu));
        const float hprev = hreg[i];                       // own column, kept in registers
        const float v = mb[i] ? (z * hprev + (1.f - z) * hh) : hprev;
        hn[i] = v;
        hreg[i] = v;
        const uint32_t hi = f2bf_rne_u(v);
        const float lo = v - bf2f(hi);
        __hip_atomic_store(hnxt + (size_t)row * H_ + col, (hi << 16) | f2bf_rne_u(lo),
                           __ATOMIC_RELAXED, __HIP_MEMORY_SCOPE_AGENT);
      }
      // drain h stores to the coherence point before signaling
      asm volatile("s_waitcnt vmcnt(0)" ::: "memory");
    }
    __syncthreads();

    if (tid == 0)
      atomicAdd(cnt + (ct & 3) * 32, 1u);   // fire-and-forget arrival

    // out stores AFTER the signal: ack latency overlaps next step's wait
    if (wave < 2){
      const int mt = wave;
      #pragma unroll
      for (int i = 0; i < 4; ++i){
        const int row = mt * 16 + (lg << 2) + i;
        const size_t oidx = ((size_t)row * T_ + te) * H_ + col;
        if (atomic_out) atomicAdd(outp + oidx, hn[i]);
        else            outp[oidx] = hn[i];
      }
    }
  }
}

// ---------------- launch ----------------

extern "C" void kernel_launch(void* const* d_in, const int* in_sizes, int n_in,
                              void* d_out, int out_size, void* d_ws, size_t ws_size,
                              hipStream_t stream) {
  const int*   tokens = (const int*)d_in[0];
  const unsigned char* mask = (const unsigned char*)d_in[1];
  const float* emb   = (const float*)d_in[2];
  const float* Wf    = (const float*)d_in[3];
  const float* Uf    = (const float*)d_in[4];
  const float* bfin  = (const float*)d_in[5];
  const float* bfrec = (const float*)d_in[6];
  const float* Wb    = (const float*)d_in[7];
  const float* Ub    = (const float*)d_in[8];
  const float* bbin  = (const float*)d_in[9];
  const float* bbrec = (const float*)d_in[10];
  float* out = (float*)d_out;
  char*  ws  = (char*)d_ws;

  // workspace layout (bytes)
  const size_t o_embb  = 0;                         // 32000*512*2      = 32,768,000
  const size_t o_wf    = 32768000;                  // 2*64*3*16*64*8*2 =  6,291,456
  const size_t o_ufhi  = 39059456;                  // 2*64*3*32*64*8*2 = 12,582,912
  const size_t o_uflo  = 51642368;                  // 12,582,912
  const size_t o_hpack = 64225280;                  // 2*2*32*1024*4    =    524,288
  const size_t o_flags = 64749568;                  // 1024
  const size_t o_bwd   = 64750592;                  // 32*512*1024*4    = 67,108,864
  const size_t need_full = o_bwd + 67108864;

  const int atomic_mode = (ws_size < need_full) ? 1 : 0;

  // reset h double-buffers + counters every call (graph replays don't re-poison)
  hipMemsetAsync(ws + o_hpack, 0, 524288 + 1024, stream);

  k_emb2bf<<<8000, 256, 0, stream>>>(emb, (unsigned short*)(ws + o_embb), 2048000);
  k_packW <<<1536, 256, 0, stream>>>(Wf, Wb, (unsigned short*)(ws + o_wf));
  k_packU <<<3072, 256, 0, stream>>>(Uf, Ub, (unsigned short*)(ws + o_ufhi),
                                             (unsigned short*)(ws + o_uflo));
  if (atomic_mode)
    hipMemsetAsync(out, 0, (size_t)out_size * sizeof(float), stream);

  k_gru<<<128, 256, 0, stream>>>(tokens, mask,
                                 (const unsigned short*)(ws + o_embb),
                                 (const unsigned short*)(ws + o_wf),
                                 (const unsigned short*)(ws + o_ufhi),
                                 (const unsigned short*)(ws + o_uflo),
                                 bfin, bfrec, bbin, bbrec,
                                 (uint32_t*)(ws + o_hpack),
                                 (uint32_t*)(ws + o_flags),
                                 out, (float*)(ws + o_bwd), atomic_mode);

  if (!atomic_mode)
    k_add<<<16384, 256, 0, stream>>>(out, (const float*)(ws + o_bwd), 4194304);
}

// Round 4
// 4639.423 us; speedup vs baseline: 1.9675x; 1.2610x over previous
//
#include <hip/hip_runtime.h>
#include <stdint.h>

#define B_    32
#define T_    512
#define H_    1024
#define H3_   3072
#define EMB_  512

typedef __bf16   bf16x8 __attribute__((ext_vector_type(8)));
typedef float    f32x4  __attribute__((ext_vector_type(4)));
typedef uint32_t u32x4  __attribute__((ext_vector_type(4)));

__device__ __forceinline__ uint32_t f2bf_rne_u(float x){
  union { float f; uint32_t u; } v; v.f = x;
  uint32_t u = v.u;
  return (u + 0x7FFFu + ((u >> 16) & 1u)) >> 16;
}
__device__ __forceinline__ float bf2f(uint32_t h16){
  union { uint32_t u; float f; } v; v.u = h16 << 16; return v.f;
}
__device__ __forceinline__ float sigm(float x){ return 1.f / (1.f + __expf(-x)); }
__device__ __forceinline__ float tanh_f(float x){ float e = __expf(2.f * x); return 1.f - 2.f / (e + 1.f); }

__device__ __forceinline__ f32x4 mfma16(bf16x8 a, bf16x8 b, f32x4 c){
  return __builtin_amdgcn_mfma_f32_16x16x32_bf16(a, b, c, 0, 0, 0);
}

// 2 u32x4 (8 packed words, word = hi16|lo16) -> hi-halves / lo-halves bf16x8
__device__ __forceinline__ bf16x8 upk_hi(u32x4 a, u32x4 b){
  u32x4 r;
  r.x = (a.x >> 16) | (a.y & 0xFFFF0000u);
  r.y = (a.z >> 16) | (a.w & 0xFFFF0000u);
  r.z = (b.x >> 16) | (b.y & 0xFFFF0000u);
  r.w = (b.z >> 16) | (b.w & 0xFFFF0000u);
  return __builtin_bit_cast(bf16x8, r);
}
__device__ __forceinline__ bf16x8 upk_lo(u32x4 a, u32x4 b){
  u32x4 r;
  r.x = (a.x & 0xFFFFu) | (a.y << 16);
  r.y = (a.z & 0xFFFFu) | (a.w << 16);
  r.z = (b.x & 0xFFFFu) | (b.y << 16);
  r.w = (b.z & 0xFFFFu) | (b.w << 16);
  return __builtin_bit_cast(bf16x8, r);
}

// ---------------- prep kernels ----------------

__global__ void k_emb2bf(const float* __restrict__ src, unsigned short* __restrict__ dst, int n8){
  int i = blockIdx.x * blockDim.x + threadIdx.x;
  if (i >= n8) return;
  const float4* s = (const float4*)src + (size_t)i * 2;
  float4 x = s[0], y = s[1];
  u32x4 o;
  o.x = f2bf_rne_u(x.x) | (f2bf_rne_u(x.y) << 16);
  o.y = f2bf_rne_u(x.z) | (f2bf_rne_u(x.w) << 16);
  o.z = f2bf_rne_u(y.x) | (f2bf_rne_u(y.y) << 16);
  o.w = f2bf_rne_u(y.z) | (f2bf_rne_u(y.w) << 16);
  ((u32x4*)dst)[i] = o;
}

// W (EMB x 3H) -> MFMA B-fragment layout [d][ct(64)][p(3)][ks(16)][lane(64)][8], bf16
__global__ void k_packW(const float* __restrict__ Wf, const float* __restrict__ Wb,
                        unsigned short* __restrict__ out){
  int idx = blockIdx.x * 256 + threadIdx.x;            // 2*64*3*16*64 = 393216
  int lane = idx & 63;
  int ks   = (idx >> 6) & 15;
  int rest = idx >> 10;                                 // d*192 + ct*3 + p
  int p  = rest % 3;
  int ct = (rest / 3) & 63;
  int d  = rest / 192;
  const float* W = d ? Wb : Wf;
  int colg = p * 1024 + ct * 16 + (lane & 15);
  int k0   = ks * 32 + ((lane >> 4) << 3);
  unsigned short* o = out + (size_t)idx * 8;
  #pragma unroll
  for (int b = 0; b < 8; ++b)
    o[b] = (unsigned short)f2bf_rne_u(W[(size_t)(k0 + b) * H3_ + colg]);
}

// U (H x 3H) -> hi/lo split fragment layout [d][ct][p][ks(32)][lane][8]
__global__ void k_packU(const float* __restrict__ Uf, const float* __restrict__ Ub,
                        unsigned short* __restrict__ ohi, unsigned short* __restrict__ olo){
  int idx = blockIdx.x * 256 + threadIdx.x;            // 2*64*3*32*64 = 786432
  int lane = idx & 63;
  int ks   = (idx >> 6) & 31;
  int rest = idx >> 11;                                 // d*192 + ct*3 + p
  int p  = rest % 3;
  int ct = (rest / 3) & 63;
  int d  = rest / 192;
  const float* U = d ? Ub : Uf;
  int colg = p * 1024 + ct * 16 + (lane & 15);
  int k0   = ks * 32 + ((lane >> 4) << 3);
  size_t o = (size_t)idx * 8;
  #pragma unroll
  for (int b = 0; b < 8; ++b){
    float u = U[(size_t)(k0 + b) * H3_ + colg];
    uint32_t hi = f2bf_rne_u(u);
    float lo = u - bf2f(hi);
    ohi[o + b] = (unsigned short)hi;
    olo[o + b] = (unsigned short)f2bf_rne_u(lo);
  }
}

__global__ void k_add(float* __restrict__ out, const float* __restrict__ add, int n4){
  int i = blockIdx.x * blockDim.x + threadIdx.x;
  if (i >= n4) return;
  f32x4 a = ((const f32x4*)out)[i];
  f32x4 b = ((const f32x4*)add)[i];
  ((f32x4*)out)[i] = a + b;
}

// ---------------- persistent GRU kernel ----------------
// grid = 128 blocks x 256 threads. blocks [0,64): fwd, [64,128): bwd.
// Each block owns 16 h-columns for all 32 batch rows; 4 waves split K.
// h broadcast: inline-asm pipelined burst of 32x global_load_dwordx4 sc1
// (L2-bypass, L3-coherent), split-waited vmcnt(16)/vmcnt(0) -> ~2 L3 RTTs
// per step instead of (possibly) 32 serialized atomic-load RTTs.

__global__ __launch_bounds__(256, 1)
void k_gru(const int* __restrict__ tokens,
           const unsigned char* __restrict__ maskp,
           const unsigned short* __restrict__ embb,
           const unsigned short* __restrict__ WF,
           const unsigned short* __restrict__ UFhi,
           const unsigned short* __restrict__ UFlo,
           const float* __restrict__ bin_f, const float* __restrict__ brec_f,
           const float* __restrict__ bin_b, const float* __restrict__ brec_b,
           uint32_t* __restrict__ hpack,   // [2 dir][2 buf][32][1024] u32 (hi16|lo16)
           uint32_t* flags,                // [2 dir][4 lines x 32 dwords]
           float* out_f, float* out_b, int atomic_out)
{
  const int blk  = blockIdx.x;
  const int d    = blk >> 6;
  const int ct   = blk & 63;
  const int tid  = threadIdx.x;
  const int lane = tid & 63;
  const int wave = tid >> 6;
  const int l15  = lane & 15;
  const int lg   = lane >> 4;
  const int mask_is32 = (maskp[1] == 0) ? 1 : 0;   // lengths>=128 => mask[0][1]==1 if byte-packed

  const float* bin  = d ? bin_b  : bin_f;
  const float* brec = d ? brec_b : brec_f;
  const int col = ct * 16 + l15;
  const float bz  = bin[col]          + brec[col];
  const float br  = bin[H_ + col]     + brec[H_ + col];
  const float bhx = bin[2 * H_ + col];
  const float bhu = brec[2 * H_ + col];

  // persistent weight fragments in registers
  bf16x8 Uh[3][8], Ul[3][8], Wr[3][4];
  {
    const size_t bu = (size_t)(d * 64 + ct) * (3 * 32 * 64 * 8);
    #pragma unroll
    for (int p = 0; p < 3; ++p)
      #pragma unroll
      for (int ks = 0; ks < 8; ++ks){
        size_t off = bu + ((size_t)(p * 32 + (wave * 8 + ks)) * 64 + lane) * 8;
        Uh[p][ks] = *(const bf16x8*)(UFhi + off);
        Ul[p][ks] = *(const bf16x8*)(UFlo + off);
      }
    const size_t bw = (size_t)(d * 64 + ct) * (3 * 16 * 64 * 8);
    #pragma unroll
    for (int p = 0; p < 3; ++p)
      #pragma unroll
      for (int ks = 0; ks < 4; ++ks){
        size_t off = bw + ((size_t)(p * 16 + (wave * 4 + ks)) * 64 + lane) * 8;
        Wr[p][ks] = *(const bf16x8*)(WF + off);
      }
  }

  __shared__ f32x4 red[4][2][4][64];   // 32 KB: [wave][mtile][slot z,r,hx,hu][lane]

  uint32_t* hp  = hpack + (size_t)d * 2 * B_ * H_;
  uint32_t* cnt = flags + d * 128;                 // 4 counters, 128 B apart
  float* outp = atomic_out ? out_f : (d ? out_b : out_f);

  const f32x4 z4 = {0.f, 0.f, 0.f, 0.f};
  float hreg[4] = {0.f, 0.f, 0.f, 0.f};   // this block's own h columns (waves 0,1)

  for (int t = 0; t < T_; ++t){
    const int te = d ? (T_ - 1 - t) : t;
    const uint32_t* hcur = hp + (size_t)(t & 1) * B_ * H_;
    uint32_t*       hnxt = hp + (size_t)((t + 1) & 1) * B_ * H_;

    const int tok0 = tokens[l15 * T_ + te];
    const int tok1 = tokens[(16 + l15) * T_ + te];

    // prefetch mask bytes for the epilogue (off the critical tail)
    bool mb[4] = {false, false, false, false};
    if (wave < 2){
      #pragma unroll
      for (int i = 0; i < 4; ++i){
        const int row = wave * 16 + (lg << 2) + i;
        const int midx = row * T_ + te;
        mb[i] = mask_is32 ? (((const int*)maskp)[midx] != 0) : (maskp[midx] != 0);
      }
    }

    f32x4 accz[2]  = {z4, z4};
    f32x4 accr[2]  = {z4, z4};
    f32x4 acchx[2] = {z4, z4};   // x-part of candidate gate
    f32x4 acchu[2] = {z4, z4};   // U-part of candidate gate

    // ---- input projection x@W: independent of h -> do it BEFORE the wait
    #pragma unroll
    for (int ks = 0; ks < 4; ++ks){
      const int koff = (wave * 4 + ks) * 32 + (lg << 3);
      bf16x8 xa0 = *(const bf16x8*)(embb + (size_t)tok0 * EMB_ + koff);
      bf16x8 xa1 = *(const bf16x8*)(embb + (size_t)tok1 * EMB_ + koff);
      accz[0]  = mfma16(xa0, Wr[0][ks], accz[0]);
      accz[1]  = mfma16(xa1, Wr[0][ks], accz[1]);
      accr[0]  = mfma16(xa0, Wr[1][ks], accr[0]);
      accr[1]  = mfma16(xa1, Wr[1][ks], accr[1]);
      acchx[0] = mfma16(xa0, Wr[2][ks], acchx[0]);
      acchx[1] = mfma16(xa1, Wr[2][ks], acchx[1]);
    }

    // ---- wait until all 64 producer blocks of this direction posted step t
    if (t > 0){
      if (wave == 0 && lane < 4){
        const uint32_t tgt = (uint32_t)(16 * t);
        while (__hip_atomic_load(cnt + lane * 32, __ATOMIC_RELAXED, __HIP_MEMORY_SCOPE_AGENT) < tgt)
          __builtin_amdgcn_s_sleep(1);
      }
      __syncthreads();
    }

    // ---- recurrent path h@U: pipelined asm burst, 32x dwordx4 sc1
    // row bases; ks slices are +128 B apart, all within imm offset range
    const uint32_t* a0 = hcur + (size_t)l15 * H_ + wave * 256 + (lg << 3);
    const uint32_t* a1 = a0 + 16 * H_;
    u32x4 e0[16], e1[16];

    // baseline the vm counter (prior out-stores / mask loads) so vmcnt(16) is exact
    asm volatile("s_waitcnt vmcnt(0)" ::: "memory");
    __builtin_amdgcn_sched_barrier(0);

    asm volatile(
      "global_load_dwordx4 %0,  %16, off sc1\n\t"
      "global_load_dwordx4 %1,  %16, off offset:16 sc1\n\t"
      "global_load_dwordx4 %2,  %16, off offset:128 sc1\n\t"
      "global_load_dwordx4 %3,  %16, off offset:144 sc1\n\t"
      "global_load_dwordx4 %4,  %16, off offset:256 sc1\n\t"
      "global_load_dwordx4 %5,  %16, off offset:272 sc1\n\t"
      "global_load_dwordx4 %6,  %16, off offset:384 sc1\n\t"
      "global_load_dwordx4 %7,  %16, off offset:400 sc1\n\t"
      "global_load_dwordx4 %8,  %17, off sc1\n\t"
      "global_load_dwordx4 %9,  %17, off offset:16 sc1\n\t"
      "global_load_dwordx4 %10, %17, off offset:128 sc1\n\t"
      "global_load_dwordx4 %11, %17, off offset:144 sc1\n\t"
      "global_load_dwordx4 %12, %17, off offset:256 sc1\n\t"
      "global_load_dwordx4 %13, %17, off offset:272 sc1\n\t"
      "global_load_dwordx4 %14, %17, off offset:384 sc1\n\t"
      "global_load_dwordx4 %15, %17, off offset:400 sc1\n\t"
      : "=&v"(e0[0]), "=&v"(e0[1]), "=&v"(e0[2]), "=&v"(e0[3]),
        "=&v"(e0[4]), "=&v"(e0[5]), "=&v"(e0[6]), "=&v"(e0[7]),
        "=&v"(e0[8]), "=&v"(e0[9]), "=&v"(e0[10]), "=&v"(e0[11]),
        "=&v"(e0[12]), "=&v"(e0[13]), "=&v"(e0[14]), "=&v"(e0[15])
      : "v"(a0), "v"(a1));
    asm volatile(
      "global_load_dwordx4 %0,  %16, off offset:512 sc1\n\t"
      "global_load_dwordx4 %1,  %16, off offset:528 sc1\n\t"
      "global_load_dwordx4 %2,  %16, off offset:640 sc1\n\t"
      "global_load_dwordx4 %3,  %16, off offset:656 sc1\n\t"
      "global_load_dwordx4 %4,  %16, off offset:768 sc1\n\t"
      "global_load_dwordx4 %5,  %16, off offset:784 sc1\n\t"
      "global_load_dwordx4 %6,  %16, off offset:896 sc1\n\t"
      "global_load_dwordx4 %7,  %16, off offset:912 sc1\n\t"
      "global_load_dwordx4 %8,  %17, off offset:512 sc1\n\t"
      "global_load_dwordx4 %9,  %17, off offset:528 sc1\n\t"
      "global_load_dwordx4 %10, %17, off offset:640 sc1\n\t"
      "global_load_dwordx4 %11, %17, off offset:656 sc1\n\t"
      "global_load_dwordx4 %12, %17, off offset:768 sc1\n\t"
      "global_load_dwordx4 %13, %17, off offset:784 sc1\n\t"
      "global_load_dwordx4 %14, %17, off offset:896 sc1\n\t"
      "global_load_dwordx4 %15, %17, off offset:912 sc1\n\t"
      : "=&v"(e1[0]), "=&v"(e1[1]), "=&v"(e1[2]), "=&v"(e1[3]),
        "=&v"(e1[4]), "=&v"(e1[5]), "=&v"(e1[6]), "=&v"(e1[7]),
        "=&v"(e1[8]), "=&v"(e1[9]), "=&v"(e1[10]), "=&v"(e1[11]),
        "=&v"(e1[12]), "=&v"(e1[13]), "=&v"(e1[14]), "=&v"(e1[15])
      : "v"(a0), "v"(a1));

    // half 0 ready (16 of 32 still outstanding)
    asm volatile("s_waitcnt vmcnt(16)" ::: "memory");
    __builtin_amdgcn_sched_barrier(0);
    #pragma unroll
    for (int ks2 = 0; ks2 < 4; ++ks2){
      const int ks = ks2;
      bf16x8 h0 = upk_hi(e0[2*ks2], e0[2*ks2+1]), L0 = upk_lo(e0[2*ks2], e0[2*ks2+1]);
      bf16x8 h1 = upk_hi(e0[8+2*ks2], e0[8+2*ks2+1]), L1 = upk_lo(e0[8+2*ks2], e0[8+2*ks2+1]);
      #pragma unroll
      for (int p = 0; p < 3; ++p){
        f32x4* acc = (p == 0) ? accz : (p == 1) ? accr : acchu;
        acc[0] = mfma16(h0, Uh[p][ks], acc[0]);
        acc[0] = mfma16(L0, Uh[p][ks], acc[0]);
        acc[0] = mfma16(h0, Ul[p][ks], acc[0]);
        acc[1] = mfma16(h1, Uh[p][ks], acc[1]);
        acc[1] = mfma16(L1, Uh[p][ks], acc[1]);
        acc[1] = mfma16(h1, Ul[p][ks], acc[1]);
      }
    }
    // half 1 ready
    asm volatile("s_waitcnt vmcnt(0)" ::: "memory");
    __builtin_amdgcn_sched_barrier(0);
    #pragma unroll
    for (int ks2 = 0; ks2 < 4; ++ks2){
      const int ks = 4 + ks2;
      bf16x8 h0 = upk_hi(e1[2*ks2], e1[2*ks2+1]), L0 = upk_lo(e1[2*ks2], e1[2*ks2+1]);
      bf16x8 h1 = upk_hi(e1[8+2*ks2], e1[8+2*ks2+1]), L1 = upk_lo(e1[8+2*ks2], e1[8+2*ks2+1]);
      #pragma unroll
      for (int p = 0; p < 3; ++p){
        f32x4* acc = (p == 0) ? accz : (p == 1) ? accr : acchu;
        acc[0] = mfma16(h0, Uh[p][ks], acc[0]);
        acc[0] = mfma16(L0, Uh[p][ks], acc[0]);
        acc[0] = mfma16(h0, Ul[p][ks], acc[0]);
        acc[1] = mfma16(h1, Uh[p][ks], acc[1]);
        acc[1] = mfma16(L1, Uh[p][ks], acc[1]);
        acc[1] = mfma16(h1, Ul[p][ks], acc[1]);
      }
    }

    // ---- cross-wave K-reduction
    red[wave][0][0][lane] = accz[0];  red[wave][0][1][lane] = accr[0];
    red[wave][0][2][lane] = acchx[0]; red[wave][0][3][lane] = acchu[0];
    red[wave][1][0][lane] = accz[1];  red[wave][1][1][lane] = accr[1];
    red[wave][1][2][lane] = acchx[1]; red[wave][1][3][lane] = acchu[1];
    __syncthreads();

    float hn[4];
    if (wave < 2){
      const int mt = wave;
      f32x4 rz  = red[0][mt][0][lane] + red[1][mt][0][lane] + red[2][mt][0][lane] + red[3][mt][0][lane];
      f32x4 rr  = red[0][mt][1][lane] + red[1][mt][1][lane] + red[2][mt][1][lane] + red[3][mt][1][lane];
      f32x4 rhx = red[0][mt][2][lane] + red[1][mt][2][lane] + red[2][mt][2][lane] + red[3][mt][2][lane];
      f32x4 rhu = red[0][mt][3][lane] + red[1][mt][3][lane] + red[2][mt][3][lane] + red[3][mt][3][lane];
      #pragma unroll
      for (int i = 0; i < 4; ++i){
        const int row = mt * 16 + (lg << 2) + i;          // C/D layout: col=lane&15, row=(lane>>4)*4+i
        const float z  = sigm(rz[i] + bz);
        const float r  = sigm(rr[i] + br);
        const float hh = tanh_f(rhx[i] + bhx + r * (rhu[i] + bhu));
        const float hprev = hreg[i];                       // own column, kept in registers
        const float v = mb[i] ? (z * hprev + (1.f - z) * hh) : hprev;
        hn[i] = v;
        hreg[i] = v;
        const uint32_t hi = f2bf_rne_u(v);
        const float lo = v - bf2f(hi);
        __hip_atomic_store(hnxt + (size_t)row * H_ + col, (hi << 16) | f2bf_rne_u(lo),
                           __ATOMIC_RELAXED, __HIP_MEMORY_SCOPE_AGENT);
      }
      // drain h stores to the coherence point before signaling
      asm volatile("s_waitcnt vmcnt(0)" ::: "memory");
    }
    __syncthreads();

    if (tid == 0)
      atomicAdd(cnt + (ct & 3) * 32, 1u);   // fire-and-forget arrival

    // out stores AFTER the signal: ack latency overlaps next step's wait
    if (wave < 2){
      const int mt = wave;
      #pragma unroll
      for (int i = 0; i < 4; ++i){
        const int row = mt * 16 + (lg << 2) + i;
        const size_t oidx = ((size_t)row * T_ + te) * H_ + col;
        if (atomic_out) atomicAdd(outp + oidx, hn[i]);
        else            outp[oidx] = hn[i];
      }
    }
  }
}

// ---------------- launch ----------------

extern "C" void kernel_launch(void* const* d_in, const int* in_sizes, int n_in,
                              void* d_out, int out_size, void* d_ws, size_t ws_size,
                              hipStream_t stream) {
  const int*   tokens = (const int*)d_in[0];
  const unsigned char* mask = (const unsigned char*)d_in[1];
  const float* emb   = (const float*)d_in[2];
  const float* Wf    = (const float*)d_in[3];
  const float* Uf    = (const float*)d_in[4];
  const float* bfin  = (const float*)d_in[5];
  const float* bfrec = (const float*)d_in[6];
  const float* Wb    = (const float*)d_in[7];
  const float* Ub    = (const float*)d_in[8];
  const float* bbin  = (const float*)d_in[9];
  const float* bbrec = (const float*)d_in[10];
  float* out = (float*)d_out;
  char*  ws  = (char*)d_ws;

  // workspace layout (bytes)
  const size_t o_embb  = 0;                         // 32000*512*2      = 32,768,000
  const size_t o_wf    = 32768000;                  // 2*64*3*16*64*8*2 =  6,291,456
  const size_t o_ufhi  = 39059456;                  // 2*64*3*32*64*8*2 = 12,582,912
  const size_t o_uflo  = 51642368;                  // 12,582,912
  const size_t o_hpack = 64225280;                  // 2*2*32*1024*4    =    524,288
  const size_t o_flags = 64749568;                  // 1024
  const size_t o_bwd   = 64750592;                  // 32*512*1024*4    = 67,108,864
  const size_t need_full = o_bwd + 67108864;

  const int atomic_mode = (ws_size < need_full) ? 1 : 0;

  // reset h double-buffers + counters every call (graph replays don't re-poison)
  hipMemsetAsync(ws + o_hpack, 0, 524288 + 1024, stream);

  k_emb2bf<<<8000, 256, 0, stream>>>(emb, (unsigned short*)(ws + o_embb), 2048000);
  k_packW <<<1536, 256, 0, stream>>>(Wf, Wb, (unsigned short*)(ws + o_wf));
  k_packU <<<3072, 256, 0, stream>>>(Uf, Ub, (unsigned short*)(ws + o_ufhi),
                                             (unsigned short*)(ws + o_uflo));
  if (atomic_mode)
    hipMemsetAsync(out, 0, (size_t)out_size * sizeof(float), stream);

  k_gru<<<128, 256, 0, stream>>>(tokens, mask,
                                 (const unsigned short*)(ws + o_embb),
                                 (const unsigned short*)(ws + o_wf),
                                 (const unsigned short*)(ws + o_ufhi),
                                 (const unsigned short*)(ws + o_uflo),
                                 bfin, bfrec, bbin, bbrec,
                                 (uint32_t*)(ws + o_hpack),
                                 (uint32_t*)(ws + o_flags),
                                 out, (float*)(ws + o_bwd), atomic_mode);

  if (!atomic_mode)
    k_add<<<16384, 256, 0, stream>>>(out, (const float*)(ws + o_bwd), 4194304);
}

// Round 5
// 3204.466 us; speedup vs baseline: 2.8485x; 1.4478x over previous
//
#include <hip/hip_runtime.h>
#include <stdint.h>

#define B_    32
#define T_    512
#define H_    1024
#define H3_   3072
#define EMB_  512

typedef __bf16   bf16x8 __attribute__((ext_vector_type(8)));
typedef float    f32x4  __attribute__((ext_vector_type(4)));
typedef uint32_t u32x4  __attribute__((ext_vector_type(4)));

__device__ __forceinline__ uint32_t f2bf_rne_u(float x){
  union { float f; uint32_t u; } v; v.f = x;
  uint32_t u = v.u;
  return (u + 0x7FFFu + ((u >> 16) & 1u)) >> 16;
}
__device__ __forceinline__ float bf2f(uint32_t h16){
  union { uint32_t u; float f; } v; v.u = h16 << 16; return v.f;
}
__device__ __forceinline__ float sigm(float x){ return 1.f / (1.f + __expf(-x)); }
__device__ __forceinline__ float tanh_f(float x){ float e = __expf(2.f * x); return 1.f - 2.f / (e + 1.f); }

__device__ __forceinline__ f32x4 mfma16(bf16x8 a, bf16x8 b, f32x4 c){
  return __builtin_amdgcn_mfma_f32_16x16x32_bf16(a, b, c, 0, 0, 0);
}

// 2 u32x4 (8 packed words, word = hi16|lo16) -> hi-halves / lo-halves bf16x8
__device__ __forceinline__ bf16x8 upk_hi(u32x4 a, u32x4 b){
  u32x4 r;
  r.x = (a.x >> 16) | (a.y & 0xFFFF0000u);
  r.y = (a.z >> 16) | (a.w & 0xFFFF0000u);
  r.z = (b.x >> 16) | (b.y & 0xFFFF0000u);
  r.w = (b.z >> 16) | (b.w & 0xFFFF0000u);
  return __builtin_bit_cast(bf16x8, r);
}
__device__ __forceinline__ bf16x8 upk_lo(u32x4 a, u32x4 b){
  u32x4 r;
  r.x = (a.x & 0xFFFFu) | (a.y << 16);
  r.y = (a.z & 0xFFFFu) | (a.w << 16);
  r.z = (b.x & 0xFFFFu) | (b.y << 16);
  r.w = (b.z & 0xFFFFu) | (b.w << 16);
  return __builtin_bit_cast(bf16x8, r);
}

// ---------------- prep kernels ----------------

__global__ void k_emb2bf(const float* __restrict__ src, unsigned short* __restrict__ dst, int n8){
  int i = blockIdx.x * blockDim.x + threadIdx.x;
  if (i >= n8) return;
  const float4* s = (const float4*)src + (size_t)i * 2;
  float4 x = s[0], y = s[1];
  u32x4 o;
  o.x = f2bf_rne_u(x.x) | (f2bf_rne_u(x.y) << 16);
  o.y = f2bf_rne_u(x.z) | (f2bf_rne_u(x.w) << 16);
  o.z = f2bf_rne_u(y.x) | (f2bf_rne_u(y.y) << 16);
  o.w = f2bf_rne_u(y.z) | (f2bf_rne_u(y.w) << 16);
  ((u32x4*)dst)[i] = o;
}

// W (EMB x 3H) -> MFMA B-fragment layout [d][ct(64)][p(3)][ks(16)][lane(64)][8], bf16
__global__ void k_packW(const float* __restrict__ Wf, const float* __restrict__ Wb,
                        unsigned short* __restrict__ out){
  int idx = blockIdx.x * 256 + threadIdx.x;            // 2*64*3*16*64 = 393216
  int lane = idx & 63;
  int ks   = (idx >> 6) & 15;
  int rest = idx >> 10;                                 // d*192 + ct*3 + p
  int p  = rest % 3;
  int ct = (rest / 3) & 63;
  int d  = rest / 192;
  const float* W = d ? Wb : Wf;
  int colg = p * 1024 + ct * 16 + (lane & 15);
  int k0   = ks * 32 + ((lane >> 4) << 3);
  unsigned short* o = out + (size_t)idx * 8;
  #pragma unroll
  for (int b = 0; b < 8; ++b)
    o[b] = (unsigned short)f2bf_rne_u(W[(size_t)(k0 + b) * H3_ + colg]);
}

// U (H x 3H) -> hi/lo split fragment layout [d][ct][p][ks(32)][lane][8]
__global__ void k_packU(const float* __restrict__ Uf, const float* __restrict__ Ub,
                        unsigned short* __restrict__ ohi, unsigned short* __restrict__ olo){
  int idx = blockIdx.x * 256 + threadIdx.x;            // 2*64*3*32*64 = 786432
  int lane = idx & 63;
  int ks   = (idx >> 6) & 31;
  int rest = idx >> 11;                                 // d*192 + ct*3 + p
  int p  = rest % 3;
  int ct = (rest / 3) & 63;
  int d  = rest / 192;
  const float* U = d ? Ub : Uf;
  int colg = p * 1024 + ct * 16 + (lane & 15);
  int k0   = ks * 32 + ((lane >> 4) << 3);
  size_t o = (size_t)idx * 8;
  #pragma unroll
  for (int b = 0; b < 8; ++b){
    float u = U[(size_t)(k0 + b) * H3_ + colg];
    uint32_t hi = f2bf_rne_u(u);
    float lo = u - bf2f(hi);
    ohi[o + b] = (unsigned short)hi;
    olo[o + b] = (unsigned short)f2bf_rne_u(lo);
  }
}

__global__ void k_add(float* __restrict__ out, const float* __restrict__ add, int n4){
  int i = blockIdx.x * blockDim.x + threadIdx.x;
  if (i >= n4) return;
  f32x4 a = ((const f32x4*)out)[i];
  f32x4 b = ((const f32x4*)add)[i];
  ((f32x4*)out)[i] = a + b;
}

// ---------------- persistent GRU kernel ----------------
// grid = 256 blocks x 256 threads = 4 independent chains (dir x row-group).
// chain = 64 blocks; block owns 16 batch rows x 16 h-cols; 4 waves K-split.
// Per-block h read = 64 KB (16 rows) -> 8 MB/step total fan-out (was 16).
// Out-stores register-batched KOUT=8 steps -> drain off the critical chain.
// One __syncthreads per step; polls are wave-autonomous; LDS reduction
// double-buffered by step parity.

#define KOUT 8

__global__ __launch_bounds__(256, 1)
void k_gru(const int* __restrict__ tokens,
           const unsigned char* __restrict__ maskp,
           const unsigned short* __restrict__ embb,
           const unsigned short* __restrict__ WF,
           const unsigned short* __restrict__ UFhi,
           const unsigned short* __restrict__ UFlo,
           const float* __restrict__ bin_f, const float* __restrict__ brec_f,
           const float* __restrict__ bin_b, const float* __restrict__ brec_b,
           uint32_t* __restrict__ hpack,   // [4 chain][2 buf][16][1024] u32 (hi16|lo16)
           uint32_t* flags,                // [4 chain][4 lines x 32 dwords]
           float* out_f, float* out_b, int atomic_out)
{
  const int blk  = blockIdx.x;
  const int d    = blk >> 7;
  const int rg   = (blk >> 6) & 1;
  const int ct   = blk & 63;
  const int chain = d * 2 + rg;
  const int tid  = threadIdx.x;
  const int lane = tid & 63;
  const int wave = tid >> 6;
  const int l15  = lane & 15;
  const int lg   = lane >> 4;
  const int mask_is32 = (maskp[1] == 0) ? 1 : 0;   // lengths>=128 => mask[0][1]==1 if byte-packed

  const float* bin  = d ? bin_b  : bin_f;
  const float* brec = d ? brec_b : brec_f;
  const int col = ct * 16 + l15;
  const float bz  = bin[col]          + brec[col];
  const float br  = bin[H_ + col]     + brec[H_ + col];
  const float bhx = bin[2 * H_ + col];
  const float bhu = brec[2 * H_ + col];

  // persistent weight fragments in registers (identical frag layout to r4)
  bf16x8 Uh[3][8], Ul[3][8], Wr[3][4];
  {
    const size_t bu = (size_t)(d * 64 + ct) * (3 * 32 * 64 * 8);
    #pragma unroll
    for (int p = 0; p < 3; ++p)
      #pragma unroll
      for (int ks = 0; ks < 8; ++ks){
        size_t off = bu + ((size_t)(p * 32 + (wave * 8 + ks)) * 64 + lane) * 8;
        Uh[p][ks] = *(const bf16x8*)(UFhi + off);
        Ul[p][ks] = *(const bf16x8*)(UFlo + off);
      }
    const size_t bw = (size_t)(d * 64 + ct) * (3 * 16 * 64 * 8);
    #pragma unroll
    for (int p = 0; p < 3; ++p)
      #pragma unroll
      for (int ks = 0; ks < 4; ++ks){
        size_t off = bw + ((size_t)(p * 16 + (wave * 4 + ks)) * 64 + lane) * 8;
        Wr[p][ks] = *(const bf16x8*)(WF + off);
      }
  }

  __shared__ f32x4 red[2][4][4][64];   // 32 KB: [parity][wave][slot z,r,hx,hu][lane]

  uint32_t* hp  = hpack + (size_t)chain * 2 * 16 * H_;
  uint32_t* cnt = flags + chain * 128;               // 4 counters, 128 B apart
  float* outp = atomic_out ? out_f : (d ? out_b : out_f);

  const f32x4 z4 = {0.f, 0.f, 0.f, 0.f};
  float hreg[4] = {0.f, 0.f, 0.f, 0.f};   // wave 0: own 4 h values (row=lg*4+i, col)
  float obuf[KOUT][4];                     // wave 0: batched out values

  for (int tb = 0; tb < T_ / KOUT; ++tb){
    #pragma unroll
    for (int ti = 0; ti < KOUT; ++ti){
      const int t   = tb * KOUT + ti;
      const int par = ti & 1;
      const int te  = d ? (T_ - 1 - t) : t;
      const uint32_t* hcur = hp + (size_t)(t & 1) * 16 * H_;
      uint32_t*       hnxt = hp + (size_t)((t + 1) & 1) * 16 * H_;

      // mask prefetch (wave 0 epilogue rows)
      bool mb[4] = {false, false, false, false};
      if (wave == 0){
        #pragma unroll
        for (int i = 0; i < 4; ++i){
          const int row = rg * 16 + (lg << 2) + i;
          const int midx = row * T_ + te;
          mb[i] = mask_is32 ? (((const int*)maskp)[midx] != 0) : (maskp[midx] != 0);
        }
      }

      f32x4 accz = z4, accr = z4, acchx = z4, acchu = z4;

      // ---- input projection x@W (h-independent; overlaps the wait)
      const int tok0 = tokens[(rg * 16 + l15) * T_ + te];
      #pragma unroll
      for (int ks = 0; ks < 4; ++ks){
        const int koff = (wave * 4 + ks) * 32 + (lg << 3);
        bf16x8 xa0 = *(const bf16x8*)(embb + (size_t)tok0 * EMB_ + koff);
        accz  = mfma16(xa0, Wr[0][ks], accz);
        accr  = mfma16(xa0, Wr[1][ks], accr);
        acchx = mfma16(xa0, Wr[2][ks], acchx);
      }

      // ---- wait until all 64 chain blocks posted step t (wave-autonomous)
      if (t > 0){
        if (lane < 4){
          const uint32_t tgt = (uint32_t)(16 * t);
          while (__hip_atomic_load(cnt + lane * 32, __ATOMIC_RELAXED, __HIP_MEMORY_SCOPE_AGENT) < tgt)
            __builtin_amdgcn_s_sleep(1);
        }
      }

      // ---- recurrent path: pipelined asm burst, 16x dwordx4 sc1 per lane
      const uint32_t* a0 = hcur + (size_t)l15 * H_ + wave * 256 + (lg << 3);
      u32x4 e0[8], e1[8];

      asm volatile("s_waitcnt vmcnt(0)" ::: "memory");
      __builtin_amdgcn_sched_barrier(0);

      asm volatile(
        "global_load_dwordx4 %0, %8, off sc1\n\t"
        "global_load_dwordx4 %1, %8, off offset:16 sc1\n\t"
        "global_load_dwordx4 %2, %8, off offset:128 sc1\n\t"
        "global_load_dwordx4 %3, %8, off offset:144 sc1\n\t"
        "global_load_dwordx4 %4, %8, off offset:256 sc1\n\t"
        "global_load_dwordx4 %5, %8, off offset:272 sc1\n\t"
        "global_load_dwordx4 %6, %8, off offset:384 sc1\n\t"
        "global_load_dwordx4 %7, %8, off offset:400 sc1\n\t"
        : "=&v"(e0[0]), "=&v"(e0[1]), "=&v"(e0[2]), "=&v"(e0[3]),
          "=&v"(e0[4]), "=&v"(e0[5]), "=&v"(e0[6]), "=&v"(e0[7])
        : "v"(a0));
      asm volatile(
        "global_load_dwordx4 %0, %8, off offset:512 sc1\n\t"
        "global_load_dwordx4 %1, %8, off offset:528 sc1\n\t"
        "global_load_dwordx4 %2, %8, off offset:640 sc1\n\t"
        "global_load_dwordx4 %3, %8, off offset:656 sc1\n\t"
        "global_load_dwordx4 %4, %8, off offset:768 sc1\n\t"
        "global_load_dwordx4 %5, %8, off offset:784 sc1\n\t"
        "global_load_dwordx4 %6, %8, off offset:896 sc1\n\t"
        "global_load_dwordx4 %7, %8, off offset:912 sc1\n\t"
        : "=&v"(e1[0]), "=&v"(e1[1]), "=&v"(e1[2]), "=&v"(e1[3]),
          "=&v"(e1[4]), "=&v"(e1[5]), "=&v"(e1[6]), "=&v"(e1[7])
        : "v"(a0));

      asm volatile("s_waitcnt vmcnt(8)" ::: "memory");
      __builtin_amdgcn_sched_barrier(0);
      #pragma unroll
      for (int ks2 = 0; ks2 < 4; ++ks2){
        bf16x8 h0 = upk_hi(e0[2*ks2], e0[2*ks2+1]);
        bf16x8 L0 = upk_lo(e0[2*ks2], e0[2*ks2+1]);
        #pragma unroll
        for (int p = 0; p < 3; ++p){
          f32x4* acc = (p == 0) ? &accz : (p == 1) ? &accr : &acchu;
          *acc = mfma16(h0, Uh[p][ks2], *acc);
          *acc = mfma16(L0, Uh[p][ks2], *acc);
          *acc = mfma16(h0, Ul[p][ks2], *acc);
        }
      }
      asm volatile("s_waitcnt vmcnt(0)" ::: "memory");
      __builtin_amdgcn_sched_barrier(0);
      #pragma unroll
      for (int ks2 = 0; ks2 < 4; ++ks2){
        const int ks = 4 + ks2;
        bf16x8 h0 = upk_hi(e1[2*ks2], e1[2*ks2+1]);
        bf16x8 L0 = upk_lo(e1[2*ks2], e1[2*ks2+1]);
        #pragma unroll
        for (int p = 0; p < 3; ++p){
          f32x4* acc = (p == 0) ? &accz : (p == 1) ? &accr : &acchu;
          *acc = mfma16(h0, Uh[p][ks], *acc);
          *acc = mfma16(L0, Uh[p][ks], *acc);
          *acc = mfma16(h0, Ul[p][ks], *acc);
        }
      }

      // ---- cross-wave K-reduction (parity double-buffered)
      red[par][wave][0][lane] = accz;
      red[par][wave][1][lane] = accr;
      red[par][wave][2][lane] = acchx;
      red[par][wave][3][lane] = acchu;
      __syncthreads();

      if (wave == 0){
        f32x4 rz  = red[par][0][0][lane] + red[par][1][0][lane] + red[par][2][0][lane] + red[par][3][0][lane];
        f32x4 rr  = red[par][0][1][lane] + red[par][1][1][lane] + red[par][2][1][lane] + red[par][3][1][lane];
        f32x4 rhx = red[par][0][2][lane] + red[par][1][2][lane] + red[par][2][2][lane] + red[par][3][2][lane];
        f32x4 rhu = red[par][0][3][lane] + red[par][1][3][lane] + red[par][2][3][lane] + red[par][3][3][lane];
        #pragma unroll
        for (int i = 0; i < 4; ++i){
          const int row = (lg << 2) + i;          // C/D layout: col=lane&15, row=(lane>>4)*4+i
          const float z  = sigm(rz[i] + bz);
          const float r  = sigm(rr[i] + br);
          const float hh = tanh_f(rhx[i] + bhx + r * (rhu[i] + bhu));
          const float hprev = hreg[i];
          const float v = mb[i] ? (z * hprev + (1.f - z) * hh) : hprev;
          hreg[i] = v;
          obuf[ti][i] = v;
          const uint32_t hi = f2bf_rne_u(v);
          const float lo = v - bf2f(hi);
          __hip_atomic_store(hnxt + (size_t)row * H_ + col, (hi << 16) | f2bf_rne_u(lo),
                             __ATOMIC_RELAXED, __HIP_MEMORY_SCOPE_AGENT);
        }
        // drain own h stores to the coherence point, then signal arrival
        asm volatile("s_waitcnt vmcnt(0)" ::: "memory");
        if (tid == 0)
          atomicAdd(cnt + (ct & 3) * 32, 1u);

        // flush batched out values once per KOUT steps (off the serial chain)
        if (ti == KOUT - 1){
          #pragma unroll
          for (int j = 0; j < KOUT; ++j){
            const int tj  = tb * KOUT + j;
            const int tej = d ? (T_ - 1 - tj) : tj;
            #pragma unroll
            for (int i = 0; i < 4; ++i){
              const int row = rg * 16 + (lg << 2) + i;
              const size_t oidx = ((size_t)row * T_ + tej) * H_ + col;
              if (atomic_out) atomicAdd(outp + oidx, obuf[j][i]);
              else            outp[oidx] = obuf[j][i];
            }
          }
        }
      }
    }
  }
}

// ---------------- launch ----------------

extern "C" void kernel_launch(void* const* d_in, const int* in_sizes, int n_in,
                              void* d_out, int out_size, void* d_ws, size_t ws_size,
                              hipStream_t stream) {
  const int*   tokens = (const int*)d_in[0];
  const unsigned char* mask = (const unsigned char*)d_in[1];
  const float* emb   = (const float*)d_in[2];
  const float* Wf    = (const float*)d_in[3];
  const float* Uf    = (const float*)d_in[4];
  const float* bfin  = (const float*)d_in[5];
  const float* bfrec = (const float*)d_in[6];
  const float* Wb    = (const float*)d_in[7];
  const float* Ub    = (const float*)d_in[8];
  const float* bbin  = (const float*)d_in[9];
  const float* bbrec = (const float*)d_in[10];
  float* out = (float*)d_out;
  char*  ws  = (char*)d_ws;

  // workspace layout (bytes)
  const size_t o_embb  = 0;                         // 32000*512*2      = 32,768,000
  const size_t o_wf    = 32768000;                  // 2*64*3*16*64*8*2 =  6,291,456
  const size_t o_ufhi  = 39059456;                  // 2*64*3*32*64*8*2 = 12,582,912
  const size_t o_uflo  = 51642368;                  // 12,582,912
  const size_t o_hpack = 64225280;                  // 4*2*16*1024*4    =    524,288
  const size_t o_flags = 64749568;                  // 2048
  const size_t o_bwd   = 64751616;                  // 32*512*1024*4    = 67,108,864
  const size_t need_full = o_bwd + 67108864;

  const int atomic_mode = (ws_size < need_full) ? 1 : 0;

  // reset h double-buffers + counters every call (graph replays don't re-poison)
  hipMemsetAsync(ws + o_hpack, 0, 524288 + 2048, stream);

  k_emb2bf<<<8000, 256, 0, stream>>>(emb, (unsigned short*)(ws + o_embb), 2048000);
  k_packW <<<1536, 256, 0, stream>>>(Wf, Wb, (unsigned short*)(ws + o_wf));
  k_packU <<<3072, 256, 0, stream>>>(Uf, Ub, (unsigned short*)(ws + o_ufhi),
                                             (unsigned short*)(ws + o_uflo));
  if (atomic_mode)
    hipMemsetAsync(out, 0, (size_t)out_size * sizeof(float), stream);

  k_gru<<<256, 256, 0, stream>>>(tokens, mask,
                                 (const unsigned short*)(ws + o_embb),
                                 (const unsigned short*)(ws + o_wf),
                                 (const unsigned short*)(ws + o_ufhi),
                                 (const unsigned short*)(ws + o_uflo),
                                 bfin, bfrec, bbin, bbrec,
                                 (uint32_t*)(ws + o_hpack),
                                 (uint32_t*)(ws + o_flags),
                                 out, (float*)(ws + o_bwd), atomic_mode);

  if (!atomic_mode)
    k_add<<<16384, 256, 0, stream>>>(out, (const float*)(ws + o_bwd), 4194304);
}